// Round 12
// baseline (164.408 us; speedup 1.0000x reference)
//
#include <hip/hip_runtime.h>
#include <hip/hip_bf16.h>
#include <math.h>

#define NN    50000
#define DEG   16
#define FIN   256
#define FOUT  128
#define EE    (NN * DEG)
#define ALPHA 0.2f

#define BM 64
#define BN 256

#define SLW 32   // f16 per node per slice: {16 hi cols | 16 lo cols}, 64 B

typedef __hip_bfloat16 bf16;
typedef _Float16 f16;
typedef __attribute__((ext_vector_type(8))) _Float16 f16x8;
typedef __attribute__((ext_vector_type(8))) short short8;
typedef __attribute__((ext_vector_type(4))) float f32x4;
typedef __attribute__((ext_vector_type(8))) unsigned short u16x8;
typedef __attribute__((ext_vector_type(8))) unsigned int u32x8;

// ---------------------------------------------------------------------------
// Build Wcat2 bf16 [256 n][512]: per n-row [Wa (256 k) | Wb (256 k)], where
// W[k][n] = (n<128 ? W_high : W_low), Wa = bf16-hi(W), Wb = bf16-lo(W).
// ---------------------------------------------------------------------------
__global__ __launch_bounds__(256) void split_w_kernel(
    const float* __restrict__ Wh, const float* __restrict__ Wl,
    bf16* __restrict__ Wcat2)
{
    const int k = blockIdx.x;    // 0..255
    const int n = threadIdx.x;   // 0..255
    const float w = (n < FOUT) ? Wh[(size_t)k * FOUT + n]
                               : Wl[(size_t)k * FOUT + (n - FOUT)];
    const bf16 hi = __float2bfloat16(w);
    const bf16 lo = __float2bfloat16(w - __bfloat162float(hi));
    Wcat2[(size_t)n * 512 + k]       = hi;
    Wcat2[(size_t)n * 512 + 256 + k] = lo;
}

// ---------------------------------------------------------------------------
// MFMA GEMM v5: NO LDS tiles, NO in-loop barriers.
//  - A fragments loaded directly from x fp32 in MFMA lane layout (lane l,
//    frag mi -> row mi*16+(l&15), cols (l>>4)*8 + s*32), truncation-split
//    to bf16 hi/lo in-register (x = hi + lo exactly at fp32; lo RTN).
//    The 4 waves of a block share the same 64 A-rows via L1.
//  - B fragments read directly from Wcat2 (512 KB, L2-resident).
//  - Fully unrolled 8-step loop; compiler software-pipelines loads across
//    steps since no barrier ever drains vmcnt.
// acc = xh@Wa + xh@Wb + xl@Wa (Ootomo bf16x3). Output h16 slice-major
// [8][NN][SLW] + sd epilogue from fp32 accumulators.
// ---------------------------------------------------------------------------
__global__ __launch_bounds__(256, 2) void gemm_mfma_kernel(
    const float* __restrict__ x, const bf16* __restrict__ Wcat2,
    const float* __restrict__ a_high, const float* __restrict__ a_low,
    f16* __restrict__ h16, float* __restrict__ sd_s, float* __restrict__ sd_d)
{
    __shared__ float sred[8 * 64];   // 2 KB, epilogue only

    const int t    = threadIdx.x;
    const int lane = t & 63;
    const int w    = t >> 6;
    const int r0   = blockIdx.x * BM;
    const int lr   = lane & 15, lg = lane >> 4;

    f32x4 acc[4][4] = {};   // [mi][ni]

    // A pointers in MFMA layout (row clamped for the 50048-tail block)
    const float* aptr[4];
#pragma unroll
    for (int mi = 0; mi < 4; ++mi)
        aptr[mi] = x + (size_t)min(r0 + mi * 16 + lr, NN - 1) * FIN + lg * 8;

    // B fragment base: lane (lr,lg) of wave w reads Wcat2[(w*64+ni*16+lr)*512
    // + s*32 + lg*8] (+256 for Wb) -- 16 B aligned, L2-hot.
    const bf16* bbase = Wcat2 + (size_t)(w * 64 + lr) * 512 + lg * 8;

#pragma unroll
    for (int s = 0; s < 8; ++s) {
        short8 fh[4], fl[4], wa[4], wb[4];

        // ---- A: load + truncation-split ----
#pragma unroll
        for (int mi = 0; mi < 4; ++mi) {
            const float4 xa = *(const float4*)(aptr[mi] + s * 32);
            const float4 xb = *(const float4*)(aptr[mi] + s * 32 + 4);
            const float f[8] = {xa.x, xa.y, xa.z, xa.w, xb.x, xb.y, xb.z, xb.w};
#pragma unroll
            for (int j = 0; j < 8; ++j) {
                const unsigned b = __float_as_uint(f[j]);
                ((unsigned short*)&fh[mi])[j] = (unsigned short)(b >> 16);
                const float hi_f = __uint_as_float(b & 0xFFFF0000u);
                ((bf16*)&fl[mi])[j] = __float2bfloat16(f[j] - hi_f);
            }
        }

        // ---- B: direct from L2 ----
#pragma unroll
        for (int ni = 0; ni < 4; ++ni) {
            wa[ni] = *(const short8*)(bbase + (size_t)ni * 16 * 512 + s * 32);
            wb[ni] = *(const short8*)(bbase + (size_t)ni * 16 * 512 + s * 32 + 256);
        }

        // ---- 48 MFMA ----
#pragma unroll
        for (int mi = 0; mi < 4; ++mi)
#pragma unroll
            for (int ni = 0; ni < 4; ++ni)
                acc[mi][ni] = __builtin_amdgcn_mfma_f32_16x16x32_bf16(
                    fh[mi], wa[ni], acc[mi][ni], 0, 0, 0);
#pragma unroll
        for (int mi = 0; mi < 4; ++mi)
#pragma unroll
            for (int ni = 0; ni < 4; ++ni)
                acc[mi][ni] = __builtin_amdgcn_mfma_f32_16x16x32_bf16(
                    fh[mi], wb[ni], acc[mi][ni], 0, 0, 0);
#pragma unroll
        for (int mi = 0; mi < 4; ++mi)
#pragma unroll
            for (int ni = 0; ni < 4; ++ni)
                acc[mi][ni] = __builtin_amdgcn_mfma_f32_16x16x32_bf16(
                    fl[mi], wa[ni], acc[mi][ni], 0, 0, 0);
    }

    // ---- h16 store, slice-major [8][NN][SLW] ----
    const int slc_base = (w < 2) ? w * 4 : (w - 2) * 4;
    const int off      = ((w < 2) ? 0 : 16) + lr;
#pragma unroll
    for (int mi = 0; mi < 4; ++mi) {
        const int rowb = r0 + mi * 16 + lg * 4;
#pragma unroll
        for (int r = 0; r < 4; ++r) {
            const int row = rowb + r;
            if (row >= NN) continue;
#pragma unroll
            for (int ni = 0; ni < 4; ++ni)
                h16[((size_t)(slc_base + ni) * NN + row) * SLW + off] =
                    (f16)acc[mi][ni][r];
        }
    }

    // ---- sd epilogue: logit scalars from fp32 acc ----
    const float* aa = (w < 2) ? a_high : a_low;
    const int cb = (w < 2) ? w * 64 : (w - 2) * 64;
    float as_[4], ad_[4];
#pragma unroll
    for (int ni = 0; ni < 4; ++ni) {
        as_[ni] = aa[cb + ni * 16 + lr];
        ad_[ni] = aa[FOUT + cb + ni * 16 + lr];
    }
#pragma unroll
    for (int mi = 0; mi < 4; ++mi)
#pragma unroll
        for (int r = 0; r < 4; ++r) {
            float ps = 0.f, pd = 0.f;
#pragma unroll
            for (int ni = 0; ni < 4; ++ni) {
                ps += acc[mi][ni][r] * as_[ni];
                pd += acc[mi][ni][r] * ad_[ni];
            }
#pragma unroll
            for (int o = 1; o < 16; o <<= 1) {
                ps += __shfl_xor(ps, o);
                pd += __shfl_xor(pd, o);
            }
            if (lr == 0) {
                const int row = mi * 16 + lg * 4 + r;
                sred[(w * 2 + 0) * 64 + row] = ps;
                sred[(w * 2 + 1) * 64 + row] = pd;
            }
        }
    __syncthreads();
    if (t < 64) {
        const int row = r0 + t;
        if (row < NN) {
            const float s_hi = sred[0 * 64 + t] + sred[2 * 64 + t];
            const float d_hi = sred[1 * 64 + t] + sred[3 * 64 + t];
            const float s_lo = sred[4 * 64 + t] + sred[6 * 64 + t];
            const float d_lo = sred[5 * 64 + t] + sred[7 * 64 + t];
            ((float2*)sd_s)[row] = make_float2(s_hi, s_lo);
            ((float2*)sd_d)[row] = make_float2(d_hi, d_lo);
        }
    }
}

// ---------------------------------------------------------------------------
// Per-edge weights, SoA: d16[e] = (u16)dst, w32[e] = fp16 wh | wl<<16.
// w = min(e,6)/(rowsum+1e-16); rowsum over UNCLIPPED e. (matches reference)
// ---------------------------------------------------------------------------
__global__ __launch_bounds__(256) void weight_kernel(
    const int* __restrict__ dst, const float* __restrict__ sd_s,
    const float* __restrict__ sd_d, unsigned short* __restrict__ d16,
    unsigned int* __restrict__ w32)
{
    const int wid  = (blockIdx.x * 256 + threadIdx.x) >> 6;
    const int lane = threadIdx.x & 63;
    if (wid >= NN) return;

    const int e    = lane & 15;
    const int d_my = dst[wid * DEG + e];
    const bool whi = (lane & 16) == 0;
    const float2 s2 = ((const float2*)sd_s)[wid];
    const float2 dd = ((const float2*)sd_d)[d_my];
    const float l   = whi ? (s2.x + dd.x) : (s2.y + dd.y);
    const float ev  = __expf(-(l >= 0.f ? l : ALPHA * l));

    float rs = ev;
    rs += __shfl_xor(rs, 1);
    rs += __shfl_xor(rs, 2);
    rs += __shfl_xor(rs, 4);
    rs += __shfl_xor(rs, 8);
    const float wn = fminf(ev, 6.f) / (rs + 1e-16f);
    const float wl = __shfl(wn, e + 16);   // lo weight for edge e

    if (lane < 16) {
        const f16 wh16 = (f16)wn, wl16 = (f16)wl;
        const unsigned a = *(const unsigned short*)&wh16;
        const unsigned b = *(const unsigned short*)&wl16;
        d16[wid * DEG + e] = (unsigned short)d_my;
        w32[wid * DEG + e] = a | (b << 16);
    }
}

// ---------------------------------------------------------------------------
// Phase B (slice, 2-half): hn[s][n] = 16*h[s][n] +/- sum_d h[s][d].
// slice = blockIdx&7 -> XCD-affine (3.2 MB slice, L2-resident).
// lane = k*8 + c*2 + hf: 8 nodes x 4 chunks x 2 edge-halves per wave.
// ---------------------------------------------------------------------------
__global__ __launch_bounds__(320) void hn_slice_kernel(
    const f16* __restrict__ h16, const unsigned short* __restrict__ d16,
    f16* __restrict__ hn16)
{
    const int sl    = blockIdx.x & 7;
    const int chunk = blockIdx.x >> 3;
    const int wv    = threadIdx.x >> 6;
    const int lane  = threadIdx.x & 63;
    const int k     = lane >> 3;
    const int c     = (lane >> 1) & 3;
    const int hf    = lane & 1;
    const int n     = (chunk * 5 + wv) * 8 + k;

    const char* hsl = (const char*)(h16 + (size_t)sl * NN * SLW);
    const float sgn = (c < 2) ? 1.f : -1.f;
    const unsigned coff = (unsigned)c * 16u;
    const unsigned noff = (unsigned)n * 64u + coff;

    const u16x8 d8 = *(const u16x8*)(d16 + n * DEG + hf * 8);
    const f16x8 own = *(const f16x8*)(hsl + noff);

    float acc[8] = {};
#pragma unroll
    for (int t = 0; t < 8; ++t) {
        const unsigned d = (unsigned)d8[t];
        const f16x8 g = *(const f16x8*)(hsl + (d * 64u + coff));
#pragma unroll
        for (int j = 0; j < 8; ++j) acc[j] = fmaf(sgn, (float)g[j], acc[j]);
    }
#pragma unroll
    for (int j = 0; j < 8; ++j) acc[j] += __shfl_xor(acc[j], 1);

    if (hf == 0) {
        f16x8 o;
#pragma unroll
        for (int j = 0; j < 8; ++j) o[j] = (f16)fmaf((float)own[j], 16.f, acc[j]);
        *(f16x8*)((char*)(hn16 + (size_t)sl * NN * SLW) + noff) = o;
    }
}

// ---------------------------------------------------------------------------
// Phase C (slice, 2-half): out[n][16sl..16sl+16) from hn slices.
// ---------------------------------------------------------------------------
__global__ __launch_bounds__(320) void out_slice_kernel(
    const f16* __restrict__ hn16, const unsigned short* __restrict__ d16,
    const unsigned int* __restrict__ w32, float* __restrict__ out)
{
    const int sl    = blockIdx.x & 7;
    const int chunk = blockIdx.x >> 3;
    const int wv    = threadIdx.x >> 6;
    const int lane  = threadIdx.x & 63;
    const int k     = lane >> 3;
    const int c     = (lane >> 1) & 3;
    const int hf    = lane & 1;
    const int n     = (chunk * 5 + wv) * 8 + k;
    const bool chi  = (c < 2);

    const char* hsl = (const char*)(hn16 + (size_t)sl * NN * SLW);
    const unsigned coff = (unsigned)c * 16u;

    const u16x8 d8 = *(const u16x8*)(d16 + n * DEG + hf * 8);
    const u32x8 w8 = *(const u32x8*)(w32 + n * DEG + hf * 8);

    float acc[8] = {};
#pragma unroll
    for (int t = 0; t < 8; ++t) {
        const unsigned wp = w8[t];
        const unsigned short wu = chi ? (unsigned short)(wp & 0xffffu)
                                      : (unsigned short)(wp >> 16);
        const float w = (float)(*(const f16*)&wu);
        const f16x8 g = *(const f16x8*)(hsl + ((unsigned)d8[t] * 64u + coff));
#pragma unroll
        for (int j = 0; j < 8; ++j) acc[j] = fmaf(w, (float)g[j], acc[j]);
    }
#pragma unroll
    for (int j = 0; j < 8; ++j) acc[j] += __shfl_xor(acc[j], 1);

    float4 v0, v1;
#pragma unroll
    for (int j = 0; j < 8; ++j) {
        const float p = __shfl_xor(acc[j], 4);   // hi chunk c <-> lo chunk c^2
        float v = 0.5f * (acc[j] + p);
        v = (v > 0.f) ? v : (__expf(v) - 1.f);
        v = fminf(v, 6.f);
        if (j < 4) ((float*)&v0)[j] = v; else ((float*)&v1)[j - 4] = v;
    }
    if (chi && hf == 0) {
        float* op = out + (size_t)n * FOUT + sl * 16 + c * 8;
        *(float4*)op       = v0;
        *(float4*)(op + 4) = v1;
    }
}

// ---------------------------------------------------------------------------
// Workspace layout (~57.6 MB):
//   [0, 25.6e6)          h16  f16 [8][NN][SLW]
//   [25.6e6, 51.2e6)     hn16 f16 [8][NN][SLW]
//   [51.2e6, 51.73e6)    Wcat2 bf16 [256][512]
//   [51.8e6, 52.2e6)     sd_s fp32 [NN][2]
//   [52.2e6, 52.6e6)     sd_d fp32 [NN][2]
//   [52.6e6, 54.2e6)     d16  u16 [EE]
//   [54.4e6, 57.6e6)     w32  u32 [EE]
// ---------------------------------------------------------------------------
extern "C" void kernel_launch(void* const* d_in, const int* in_sizes, int n_in,
                              void* d_out, int out_size, void* d_ws, size_t ws_size,
                              hipStream_t stream)
{
    const float* x      = (const float*)d_in[0];
    const int*   edge   = (const int*)d_in[1];
    const float* Wh     = (const float*)d_in[2];
    const float* Wl     = (const float*)d_in[3];
    const float* a_high = (const float*)d_in[4];
    const float* a_low  = (const float*)d_in[5];
    const int*   dstv   = edge + EE;

    char* ws = (char*)d_ws;
    f16*   h16   = (f16*)ws;
    f16*   hn16  = (f16*)(ws + 25600000);
    bf16*  Wcat2 = (bf16*)(ws + 51200000);
    float* sd_s  = (float*)(ws + 51800000);
    float* sd_d  = (float*)(ws + 52200000);
    unsigned short* d16 = (unsigned short*)(ws + 52600000);
    unsigned int*   w32 = (unsigned int*)(ws + 54400000);

    split_w_kernel<<<dim3(256), dim3(256), 0, stream>>>(Wh, Wl, Wcat2);
    gemm_mfma_kernel<<<dim3((NN + BM - 1) / BM), dim3(256), 0, stream>>>(
        x, Wcat2, a_high, a_low, h16, sd_s, sd_d);
    weight_kernel<<<dim3((NN + 3) / 4), dim3(256), 0, stream>>>(dstv, sd_s, sd_d, d16, w32);
    hn_slice_kernel<<<dim3(8 * 1250), dim3(320), 0, stream>>>(h16, d16, hn16);
    out_slice_kernel<<<dim3(8 * 1250), dim3(320), 0, stream>>>(hn16, d16, w32, (float*)d_out);
}

// Round 13
// 131.894 us; speedup vs baseline: 1.2465x; 1.2465x over previous
//
#include <hip/hip_runtime.h>
#include <hip/hip_bf16.h>
#include <math.h>

#define NN    50000
#define DEG   16
#define FIN   256
#define FOUT  128
#define EE    (NN * DEG)
#define ALPHA 0.2f

#define BM 64
#define BN 256

#define SLW 32   // f16 per node per slice: {16 hi cols | 16 lo cols}, 64 B

typedef __hip_bfloat16 bf16;
typedef _Float16 f16;
typedef __attribute__((ext_vector_type(8))) _Float16 f16x8;
typedef __attribute__((ext_vector_type(8))) short short8;
typedef __attribute__((ext_vector_type(4))) float f32x4;
typedef __attribute__((ext_vector_type(8))) unsigned short u16x8;
typedef __attribute__((ext_vector_type(8))) unsigned int u32x8;

// ---------------------------------------------------------------------------
// Build Wcat2 bf16 [256 n][512]: per n-row [Wa (256 k) | Wb (256 k)], where
// W[k][n] = (n<128 ? W_high : W_low), Wa = bf16-hi(W), Wb = bf16-lo(W).
// ---------------------------------------------------------------------------
__global__ __launch_bounds__(256) void split_w_kernel(
    const float* __restrict__ Wh, const float* __restrict__ Wl,
    bf16* __restrict__ Wcat2)
{
    const int k = blockIdx.x;    // 0..255
    const int n = threadIdx.x;   // 0..255
    const float w = (n < FOUT) ? Wh[(size_t)k * FOUT + n]
                               : Wl[(size_t)k * FOUT + (n - FOUT)];
    const bf16 hi = __float2bfloat16(w);
    const bf16 lo = __float2bfloat16(w - __bfloat162float(hi));
    Wcat2[(size_t)n * 512 + k]       = hi;
    Wcat2[(size_t)n * 512 + 256 + k] = lo;
}

// ---------------------------------------------------------------------------
// MFMA GEMM v6: round-8 LDS-staged structure, but 8 waves / 512 threads.
// Wave w owns 32 N-cols (2 ni frags) -> acc 32 VGPR, <=128 VGPR total ->
// 2 blocks/CU x 8 waves = 16 waves/CU: cross-block overlap hides the
// per-barrier load drain (the round-8..12 invariant was TLP, not pipeline
// shape). Per step: stage A (reg-split x) + glds B, barrier, 24 MFMA.
// acc = xh@Wa + xh@Wb + xl@Wa (Ootomo bf16x3). Output h16 slice-major
// [8][NN][SLW] + sd epilogue from fp32 accumulators.
// ---------------------------------------------------------------------------
__global__ __launch_bounds__(512, 4) void gemm_mfma_kernel(
    const float* __restrict__ x, const bf16* __restrict__ Wcat2,
    const float* __restrict__ a_high, const float* __restrict__ a_low,
    f16* __restrict__ h16, float* __restrict__ sd_s, float* __restrict__ sd_d)
{
    __shared__ bf16 Ah[BM * 32];   // 4 KB (reused as sred in epilogue)
    __shared__ bf16 Al[BM * 32];   // 4 KB
    __shared__ bf16 Ba[BN * 32];   // 16 KB (Wa)
    __shared__ bf16 Bb[BN * 32];   // 16 KB (Wb)

    const int t    = threadIdx.x;
    const int lane = t & 63;
    const int w    = t >> 6;       // 0..7
    const int r0   = blockIdx.x * BM;
    const int lr   = lane & 15, lg = lane >> 4;

    f32x4 acc[4][2] = {};   // [mi][ni]

    // A staging: thread t owns x[r0 + (t>>3)][(t&7)*4 .. +4] per 32-col step
    const int arow = t >> 3;
    const int sub  = t & 7;
    const float* xsrc = x + (size_t)min(r0 + arow, NN - 1) * FIN + sub * 4;
    const int awaddr = arow * 64 + ((((sub >> 1)) + (arow >> 1)) & 3) * 16
                     + (sub & 1) * 8;

    // B staging: 2 16-B chunks per thread per tile (inverse-swizzled source)
    int bro[2], bsl[2];
#pragma unroll
    for (int i = 0; i < 2; ++i) {
        const int idx = t + i * 512;
        bro[i] = idx >> 2;
        bsl[i] = ((idx & 3) - (bro[i] >> 1)) & 3;
    }

    float4 xr = *(const float4*)(xsrc + 0);   // x(0)

#pragma unroll
    for (int s = 0; s < 8; ++s) {
        __syncthreads();   // previous step's LDS reads done (no-op at s=0)

        // ---- stage A(s): split this step's x regs to bf16 hi/lo ----
        {
            short4 hi4, lo4;
            const float f[4] = {xr.x, xr.y, xr.z, xr.w};
#pragma unroll
            for (int j = 0; j < 4; ++j) {
                const bf16 h = __float2bfloat16(f[j]);
                const bf16 l = __float2bfloat16(f[j] - __bfloat162float(h));
                ((bf16*)&hi4)[j] = h;
                ((bf16*)&lo4)[j] = l;
            }
            *(short4*)((char*)Ah + awaddr) = hi4;
            *(short4*)((char*)Al + awaddr) = lo4;
        }

        // ---- stage B(s): 4 glds ----
        const int c0 = s * 32;
#pragma unroll
        for (int i = 0; i < 2; ++i) {
            __builtin_amdgcn_global_load_lds(
                (const __attribute__((address_space(1))) void*)
                    (Wcat2 + (size_t)bro[i] * 512 + c0 + bsl[i] * 8),
                (__attribute__((address_space(3))) void*)((char*)Ba + (t + i * 512) * 16),
                16, 0, 0);
            __builtin_amdgcn_global_load_lds(
                (const __attribute__((address_space(1))) void*)
                    (Wcat2 + (size_t)bro[i] * 512 + 256 + c0 + bsl[i] * 8),
                (__attribute__((address_space(3))) void*)((char*)Bb + (t + i * 512) * 16),
                16, 0, 0);
        }

        // ---- prefetch x(s+1) ----
        if (s < 7) xr = *(const float4*)(xsrc + (s + 1) * 32);

        __syncthreads();   // tiles ready

        // ---- 24 MFMA ----
        short8 fh[4], fl[4], wa[2], wb[2];
#pragma unroll
        for (int mi = 0; mi < 4; ++mi) {
            const int row  = mi * 16 + lr;
            const int slot = (lg + (row >> 1)) & 3;
            fh[mi] = *(const short8*)((const char*)Ah + row * 64 + slot * 16);
            fl[mi] = *(const short8*)((const char*)Al + row * 64 + slot * 16);
        }
#pragma unroll
        for (int ni = 0; ni < 2; ++ni) {
            const int row  = w * 32 + ni * 16 + lr;
            const int slot = (lg + (row >> 1)) & 3;
            wa[ni] = *(const short8*)((const char*)Ba + row * 64 + slot * 16);
            wb[ni] = *(const short8*)((const char*)Bb + row * 64 + slot * 16);
        }
#pragma unroll
        for (int mi = 0; mi < 4; ++mi)
#pragma unroll
            for (int ni = 0; ni < 2; ++ni)
                acc[mi][ni] = __builtin_amdgcn_mfma_f32_16x16x32_bf16(
                    fh[mi], wa[ni], acc[mi][ni], 0, 0, 0);
#pragma unroll
        for (int mi = 0; mi < 4; ++mi)
#pragma unroll
            for (int ni = 0; ni < 2; ++ni)
                acc[mi][ni] = __builtin_amdgcn_mfma_f32_16x16x32_bf16(
                    fh[mi], wb[ni], acc[mi][ni], 0, 0, 0);
#pragma unroll
        for (int mi = 0; mi < 4; ++mi)
#pragma unroll
            for (int ni = 0; ni < 2; ++ni)
                acc[mi][ni] = __builtin_amdgcn_mfma_f32_16x16x32_bf16(
                    fl[mi], wa[ni], acc[mi][ni], 0, 0, 0);
    }

    // ---- h16 store, slice-major [8][NN][SLW] ----
    // wave w covers cols w*32 + ni*16 + lr: slice = (w<4)? w*2+ni : (w-4)*2+ni
    const int off = ((w < 4) ? 0 : 16) + lr;
#pragma unroll
    for (int mi = 0; mi < 4; ++mi) {
        const int rowb = r0 + mi * 16 + lg * 4;
#pragma unroll
        for (int r = 0; r < 4; ++r) {
            const int row = rowb + r;
            if (row >= NN) continue;
#pragma unroll
            for (int ni = 0; ni < 2; ++ni) {
                const int slc = ((w < 4) ? w * 2 : (w - 4) * 2) + ni;
                h16[((size_t)slc * NN + row) * SLW + off] = (f16)acc[mi][ni][r];
            }
        }
    }

    __syncthreads();   // K-loop LDS reads done before sred reuse

    // ---- sd epilogue: logit scalars from fp32 acc ----
    const float* aa = (w < 4) ? a_high : a_low;
    const int cb = (w < 4) ? w * 32 : (w - 4) * 32;
    float as_[2], ad_[2];
#pragma unroll
    for (int ni = 0; ni < 2; ++ni) {
        as_[ni] = aa[cb + ni * 16 + lr];
        ad_[ni] = aa[FOUT + cb + ni * 16 + lr];
    }
    float* sred = (float*)Ah;   // 8 waves * 2 scalars * 64 rows = 4 KB
#pragma unroll
    for (int mi = 0; mi < 4; ++mi)
#pragma unroll
        for (int r = 0; r < 4; ++r) {
            float ps = 0.f, pd = 0.f;
#pragma unroll
            for (int ni = 0; ni < 2; ++ni) {
                ps += acc[mi][ni][r] * as_[ni];
                pd += acc[mi][ni][r] * ad_[ni];
            }
#pragma unroll
            for (int o = 1; o < 16; o <<= 1) {
                ps += __shfl_xor(ps, o);
                pd += __shfl_xor(pd, o);
            }
            if (lr == 0) {
                const int row = mi * 16 + lg * 4 + r;
                sred[(w * 2 + 0) * 64 + row] = ps;
                sred[(w * 2 + 1) * 64 + row] = pd;
            }
        }
    __syncthreads();
    if (t < 64) {
        const int row = r0 + t;
        if (row < NN) {
            float s_hi = 0.f, d_hi = 0.f, s_lo = 0.f, d_lo = 0.f;
#pragma unroll
            for (int ww = 0; ww < 4; ++ww) {
                s_hi += sred[(ww * 2 + 0) * 64 + t];
                d_hi += sred[(ww * 2 + 1) * 64 + t];
                s_lo += sred[((ww + 4) * 2 + 0) * 64 + t];
                d_lo += sred[((ww + 4) * 2 + 1) * 64 + t];
            }
            ((float2*)sd_s)[row] = make_float2(s_hi, s_lo);
            ((float2*)sd_d)[row] = make_float2(d_hi, d_lo);
        }
    }
}

// ---------------------------------------------------------------------------
// Per-edge weights, SoA: d16[e] = (u16)dst, w32[e] = fp16 wh | wl<<16.
// w = min(e,6)/(rowsum+1e-16); rowsum over UNCLIPPED e. (matches reference)
// ---------------------------------------------------------------------------
__global__ __launch_bounds__(256) void weight_kernel(
    const int* __restrict__ dst, const float* __restrict__ sd_s,
    const float* __restrict__ sd_d, unsigned short* __restrict__ d16,
    unsigned int* __restrict__ w32)
{
    const int wid  = (blockIdx.x * 256 + threadIdx.x) >> 6;
    const int lane = threadIdx.x & 63;
    if (wid >= NN) return;

    const int e    = lane & 15;
    const int d_my = dst[wid * DEG + e];
    const bool whi = (lane & 16) == 0;
    const float2 s2 = ((const float2*)sd_s)[wid];
    const float2 dd = ((const float2*)sd_d)[d_my];
    const float l   = whi ? (s2.x + dd.x) : (s2.y + dd.y);
    const float ev  = __expf(-(l >= 0.f ? l : ALPHA * l));

    float rs = ev;
    rs += __shfl_xor(rs, 1);
    rs += __shfl_xor(rs, 2);
    rs += __shfl_xor(rs, 4);
    rs += __shfl_xor(rs, 8);
    const float wn = fminf(ev, 6.f) / (rs + 1e-16f);
    const float wl = __shfl(wn, e + 16);   // lo weight for edge e

    if (lane < 16) {
        const f16 wh16 = (f16)wn, wl16 = (f16)wl;
        const unsigned a = *(const unsigned short*)&wh16;
        const unsigned b = *(const unsigned short*)&wl16;
        d16[wid * DEG + e] = (unsigned short)d_my;
        w32[wid * DEG + e] = a | (b << 16);
    }
}

// ---------------------------------------------------------------------------
// Phase B (slice, 2-half): hn[s][n] = 16*h[s][n] +/- sum_d h[s][d].
// slice = blockIdx&7 -> XCD-affine (3.2 MB slice, L2-resident).
// lane = k*8 + c*2 + hf: 8 nodes x 4 chunks x 2 edge-halves per wave.
// ---------------------------------------------------------------------------
__global__ __launch_bounds__(320) void hn_slice_kernel(
    const f16* __restrict__ h16, const unsigned short* __restrict__ d16,
    f16* __restrict__ hn16)
{
    const int sl    = blockIdx.x & 7;
    const int chunk = blockIdx.x >> 3;
    const int wv    = threadIdx.x >> 6;
    const int lane  = threadIdx.x & 63;
    const int k     = lane >> 3;
    const int c     = (lane >> 1) & 3;
    const int hf    = lane & 1;
    const int n     = (chunk * 5 + wv) * 8 + k;

    const char* hsl = (const char*)(h16 + (size_t)sl * NN * SLW);
    const float sgn = (c < 2) ? 1.f : -1.f;
    const unsigned coff = (unsigned)c * 16u;
    const unsigned noff = (unsigned)n * 64u + coff;

    const u16x8 d8 = *(const u16x8*)(d16 + n * DEG + hf * 8);
    const f16x8 own = *(const f16x8*)(hsl + noff);

    float acc[8] = {};
#pragma unroll
    for (int t = 0; t < 8; ++t) {
        const unsigned d = (unsigned)d8[t];
        const f16x8 g = *(const f16x8*)(hsl + (d * 64u + coff));
#pragma unroll
        for (int j = 0; j < 8; ++j) acc[j] = fmaf(sgn, (float)g[j], acc[j]);
    }
#pragma unroll
    for (int j = 0; j < 8; ++j) acc[j] += __shfl_xor(acc[j], 1);

    if (hf == 0) {
        f16x8 o;
#pragma unroll
        for (int j = 0; j < 8; ++j) o[j] = (f16)fmaf((float)own[j], 16.f, acc[j]);
        *(f16x8*)((char*)(hn16 + (size_t)sl * NN * SLW) + noff) = o;
    }
}

// ---------------------------------------------------------------------------
// Phase C (slice, 2-half): out[n][16sl..16sl+16) from hn slices.
// ---------------------------------------------------------------------------
__global__ __launch_bounds__(320) void out_slice_kernel(
    const f16* __restrict__ hn16, const unsigned short* __restrict__ d16,
    const unsigned int* __restrict__ w32, float* __restrict__ out)
{
    const int sl    = blockIdx.x & 7;
    const int chunk = blockIdx.x >> 3;
    const int wv    = threadIdx.x >> 6;
    const int lane  = threadIdx.x & 63;
    const int k     = lane >> 3;
    const int c     = (lane >> 1) & 3;
    const int hf    = lane & 1;
    const int n     = (chunk * 5 + wv) * 8 + k;
    const bool chi  = (c < 2);

    const char* hsl = (const char*)(hn16 + (size_t)sl * NN * SLW);
    const unsigned coff = (unsigned)c * 16u;

    const u16x8 d8 = *(const u16x8*)(d16 + n * DEG + hf * 8);
    const u32x8 w8 = *(const u32x8*)(w32 + n * DEG + hf * 8);

    float acc[8] = {};
#pragma unroll
    for (int t = 0; t < 8; ++t) {
        const unsigned wp = w8[t];
        const unsigned short wu = chi ? (unsigned short)(wp & 0xffffu)
                                      : (unsigned short)(wp >> 16);
        const float w = (float)(*(const f16*)&wu);
        const f16x8 g = *(const f16x8*)(hsl + ((unsigned)d8[t] * 64u + coff));
#pragma unroll
        for (int j = 0; j < 8; ++j) acc[j] = fmaf(w, (float)g[j], acc[j]);
    }
#pragma unroll
    for (int j = 0; j < 8; ++j) acc[j] += __shfl_xor(acc[j], 1);

    float4 v0, v1;
#pragma unroll
    for (int j = 0; j < 8; ++j) {
        const float p = __shfl_xor(acc[j], 4);   // hi chunk c <-> lo chunk c^2
        float v = 0.5f * (acc[j] + p);
        v = (v > 0.f) ? v : (__expf(v) - 1.f);
        v = fminf(v, 6.f);
        if (j < 4) ((float*)&v0)[j] = v; else ((float*)&v1)[j - 4] = v;
    }
    if (chi && hf == 0) {
        float* op = out + (size_t)n * FOUT + sl * 16 + c * 8;
        *(float4*)op       = v0;
        *(float4*)(op + 4) = v1;
    }
}

// ---------------------------------------------------------------------------
// Workspace layout (~57.6 MB):
//   [0, 25.6e6)          h16  f16 [8][NN][SLW]
//   [25.6e6, 51.2e6)     hn16 f16 [8][NN][SLW]
//   [51.2e6, 51.73e6)    Wcat2 bf16 [256][512]
//   [51.8e6, 52.2e6)     sd_s fp32 [NN][2]
//   [52.2e6, 52.6e6)     sd_d fp32 [NN][2]
//   [52.6e6, 54.2e6)     d16  u16 [EE]
//   [54.4e6, 57.6e6)     w32  u32 [EE]
// ---------------------------------------------------------------------------
extern "C" void kernel_launch(void* const* d_in, const int* in_sizes, int n_in,
                              void* d_out, int out_size, void* d_ws, size_t ws_size,
                              hipStream_t stream)
{
    const float* x      = (const float*)d_in[0];
    const int*   edge   = (const int*)d_in[1];
    const float* Wh     = (const float*)d_in[2];
    const float* Wl     = (const float*)d_in[3];
    const float* a_high = (const float*)d_in[4];
    const float* a_low  = (const float*)d_in[5];
    const int*   dstv   = edge + EE;

    char* ws = (char*)d_ws;
    f16*   h16   = (f16*)ws;
    f16*   hn16  = (f16*)(ws + 25600000);
    bf16*  Wcat2 = (bf16*)(ws + 51200000);
    float* sd_s  = (float*)(ws + 51800000);
    float* sd_d  = (float*)(ws + 52200000);
    unsigned short* d16 = (unsigned short*)(ws + 52600000);
    unsigned int*   w32 = (unsigned int*)(ws + 54400000);

    split_w_kernel<<<dim3(256), dim3(256), 0, stream>>>(Wh, Wl, Wcat2);
    gemm_mfma_kernel<<<dim3((NN + BM - 1) / BM), dim3(512), 0, stream>>>(
        x, Wcat2, a_high, a_low, h16, sd_s, sd_d);
    weight_kernel<<<dim3((NN + 3) / 4), dim3(256), 0, stream>>>(dstv, sd_s, sd_d, d16, w32);
    hn_slice_kernel<<<dim3(8 * 1250), dim3(320), 0, stream>>>(h16, d16, hn16);
    out_slice_kernel<<<dim3(8 * 1250), dim3(320), 0, stream>>>(hn16, d16, w32, (float*)d_out);
}